// Round 12
// baseline (228.945 us; speedup 1.0000x reference)
//
#include <hip/hip_runtime.h>
#include <math.h>

#define N_NODES 20000
#define N_EDGES 50000
#define N_SLOTS 256   // N_PAIRS * 2 flattened targets
#define N_PAIRS 128
#define CAP 64        // max incident edges per slot (deg ~ Poisson(5))
#define MSTRIDE 16384 // floats per transposed-matrix slot in ws
#define NMAT 19
#define TFLAG (1 << 30)

// ---------- helpers ----------
__device__ __forceinline__ float4 relu4(float4 v) {
    return make_float4(fmaxf(v.x, 0.f), fmaxf(v.y, 0.f), fmaxf(v.z, 0.f), fmaxf(v.w, 0.f));
}
__device__ __forceinline__ float4 add4(float4 a, float4 b) {
    return make_float4(a.x + b.x, a.y + b.y, a.z + b.z, a.w + b.w);
}
__device__ __forceinline__ void fma4(float4& acc, const float4 w, const float s) {
    acc.x = fmaf(w.x, s, acc.x); acc.y = fmaf(w.y, s, acc.y);
    acc.z = fmaf(w.z, s, acc.z); acc.w = fmaf(w.w, s, acc.w);
}
#define F4Z make_float4(0.f, 0.f, 0.f, 0.f)

// ===== 8-group K-split (256-thread blocks): group g covers k-chunks [4g,4g+4) =====
// R7 = measured-best shape (200.9 us). R8 (2 live accs: spill), R10 (512 thr:
// barrier overhead), R11 (pair tail: VGPR 256 kernel-wide) all regressed.
__device__ __forceinline__ float4 mv_ks1_g8(const float* __restrict__ WT,
                                            const float* __restrict__ xv128,
                                            int g, int jj) {
    const float4* W4 = (const float4*)WT;
    const float4* x4 = (const float4*)xv128;
    float4 acc = F4Z;
#pragma unroll
    for (int kk4 = 0; kk4 < 4; ++kk4) {
        int k4 = g * 4 + kk4;
        float4 xv = x4[k4];
        fma4(acc, W4[(k4 * 4 + 0) * 32 + jj], xv.x);
        fma4(acc, W4[(k4 * 4 + 1) * 32 + jj], xv.y);
        fma4(acc, W4[(k4 * 4 + 2) * 32 + jj], xv.z);
        fma4(acc, W4[(k4 * 4 + 3) * 32 + jj], xv.w);
    }
    return acc;
}
__device__ __forceinline__ float4 mv_ks1_g8_64(const float* __restrict__ WT,
                                               const float* __restrict__ xv128,
                                               int g, int jj) {
    const float4* W4 = (const float4*)WT;
    const float4* x4 = (const float4*)xv128;
    int j16 = jj & 15;
    float4 acc = F4Z;
#pragma unroll
    for (int kk4 = 0; kk4 < 4; ++kk4) {
        int k4 = g * 4 + kk4;
        float4 xv = x4[k4];
        fma4(acc, W4[(k4 * 4 + 0) * 16 + j16], xv.x);
        fma4(acc, W4[(k4 * 4 + 1) * 16 + j16], xv.y);
        fma4(acc, W4[(k4 * 4 + 2) * 16 + j16], xv.z);
        fma4(acc, W4[(k4 * 4 + 3) * 16 + j16], xv.w);
    }
    return acc;
}
// ONE acc[8] set live per scope (spill guard — R8 lesson)
__device__ __forceinline__ void mv8_g8(const float* __restrict__ WT,
                                       const float* __restrict__ xs,
                                       int g, int jj, float4* acc) {
    const float4* W4 = (const float4*)WT;
    const float4* x4 = (const float4*)xs;
#pragma unroll
    for (int kk4 = 0; kk4 < 4; ++kk4) {
        int k4 = g * 4 + kk4;
        float4 w0 = W4[(k4 * 4 + 0) * 32 + jj];
        float4 w1 = W4[(k4 * 4 + 1) * 32 + jj];
        float4 w2 = W4[(k4 * 4 + 2) * 32 + jj];
        float4 w3 = W4[(k4 * 4 + 3) * 32 + jj];
#pragma unroll
        for (int e = 0; e < 8; ++e) {
            float4 xv = x4[e * 32 + k4];
            fma4(acc[e], w0, xv.x); fma4(acc[e], w1, xv.y);
            fma4(acc[e], w2, xv.z); fma4(acc[e], w3, xv.w);
        }
    }
}
__device__ __forceinline__ float4 comb1_g8(const float4* pb, int jj) {
    float4 s = pb[jj];
#pragma unroll
    for (int gp = 1; gp < 8; ++gp) s = add4(s, pb[gp * 32 + jj]);
    return s;
}
__device__ __forceinline__ float4 comb8_g8(const float4* pb, int it, int jj) {
    float4 s = pb[it * 32 + jj];
#pragma unroll
    for (int gp = 1; gp < 8; ++gp) s = add4(s, pb[(gp * 8 + it) * 32 + jj]);
    return s;
}

// ===== 4-group variants for the 128-thread pair kernel =====
__device__ __forceinline__ float4 mv_ks1(const float* __restrict__ WT,
                                         const float* __restrict__ xv128,
                                         int g, int jj) {
    const float4* W4 = (const float4*)WT;
    const float4* x4 = (const float4*)xv128;
    float4 acc = F4Z;
#pragma unroll 2
    for (int kk4 = 0; kk4 < 8; ++kk4) {
        int k4 = g * 8 + kk4;
        float4 xv = x4[k4];
        fma4(acc, W4[(k4 * 4 + 0) * 32 + jj], xv.x);
        fma4(acc, W4[(k4 * 4 + 1) * 32 + jj], xv.y);
        fma4(acc, W4[(k4 * 4 + 2) * 32 + jj], xv.z);
        fma4(acc, W4[(k4 * 4 + 3) * 32 + jj], xv.w);
    }
    return acc;
}
__device__ __forceinline__ float4 mv_ks1_64(const float* __restrict__ WT,
                                            const float* __restrict__ xv128,
                                            int g, int jj) {
    const float4* W4 = (const float4*)WT;
    const float4* x4 = (const float4*)xv128;
    int j16 = jj & 15;
    float4 acc = F4Z;
#pragma unroll 2
    for (int kk4 = 0; kk4 < 8; ++kk4) {
        int k4 = g * 8 + kk4;
        float4 xv = x4[k4];
        fma4(acc, W4[(k4 * 4 + 0) * 16 + j16], xv.x);
        fma4(acc, W4[(k4 * 4 + 1) * 16 + j16], xv.y);
        fma4(acc, W4[(k4 * 4 + 2) * 16 + j16], xv.z);
        fma4(acc, W4[(k4 * 4 + 3) * 16 + j16], xv.w);
    }
    return acc;
}
__device__ __forceinline__ float4 comb1(const float4* pb, int jj) {
    return add4(add4(pb[jj], pb[32 + jj]), add4(pb[64 + jj], pb[96 + jj]));
}

// ---------- kernels ----------

// fused: weight transpose (blocks 0..71) + per-slot edge scan + target-flagging
__global__ __launch_bounds__(256) void k_prep_tr(
    const int* __restrict__ ei, const int* __restrict__ tp,
    const float* __restrict__ inW, const float* __restrict__ ftW,
    const float* __restrict__ teW2, const float* __restrict__ aiW,
    const float* __restrict__ aoW, const float* __restrict__ opW,
    const float* __restrict__ o1W, const float* __restrict__ o2W,
    const float* __restrict__ l1W, const float* __restrict__ l2W,
    float* __restrict__ WT, int* __restrict__ cnt, int2* __restrict__ lst) {
    __shared__ float tile[32][129];
    __shared__ int tps[N_SLOTS];
    __shared__ int lc;
    const int b = blockIdx.x;
    if (threadIdx.x == 0) lc = 0;
    if (b < 72) {  // block-uniform branch: barriers inside are legal
        int m, r0, rows;
        if (b < 68) { m = b >> 2; r0 = (b & 3) * 32; rows = 128; }
        else { int mm = b - 68; m = 17 + (mm >> 1); r0 = (mm & 1) * 32; rows = 64; }
        const float* src;
        if (m == 0) src = inW;
        else if (m <= 2) src = ftW + (m - 1) * MSTRIDE;
        else if (m <= 4) src = teW2 + (m - 3) * MSTRIDE;
        else if (m <= 10) src = aiW + (m - 5) * MSTRIDE;  // q0,k0,v0,q1,k1,v1
        else if (m <= 12) src = aoW + (m - 11) * MSTRIDE;
        else if (m <= 14) src = opW + (m - 13) * MSTRIDE;
        else if (m == 15) src = o1W;
        else if (m == 16) src = l1W;
        else if (m == 17) src = o2W;
        else src = l2W;
        float* dst = WT + m * MSTRIDE;
        for (int idx = threadIdx.x; idx < 32 * 128; idx += 256) {
            int r = idx >> 7, c = idx & 127;
            tile[r][c] = src[(r0 + r) * 128 + c];
        }
        __syncthreads();
        for (int idx = threadIdx.x; idx < 128 * 32; idx += 256) {
            int k = idx >> 5, jr = idx & 31;
            dst[k * rows + r0 + jr] = tile[jr][k];
        }
    }
    for (int i = threadIdx.x; i < N_SLOTS; i += 256) tps[i] = tp[i];
    __syncthreads();
    // per-slot incident-edge scan
    const int u = tps[b];
    const int4* src4 = (const int4*)ei;
    const int4* dst4 = (const int4*)(ei + N_EDGES);
    for (int e4 = threadIdx.x; e4 < N_EDGES / 4; e4 += 256) {
        int4 s = src4[e4];
        int4 d = dst4[e4];
        int ss[4] = {s.x, s.y, s.z, s.w};
        int dd[4] = {d.x, d.y, d.z, d.w};
#pragma unroll
        for (int t = 0; t < 4; ++t) {
            if (ss[t] == u || dd[t] == u) {
                int nbr = (ss[t] == u) ? dd[t] : ss[t];
                int pos = atomicAdd(&lc, 1);
                if (pos < CAP) lst[b * CAP + pos] = make_int2(e4 * 4 + t, nbr);
            }
        }
    }
    __syncthreads();
    if (threadIdx.x == 0) cnt[b] = lc;
    // flag entries whose neighbor is itself a target (race-avoidance in k_layer)
    int c = min(lc, CAP);
    if (threadIdx.x < c) {
        int2 en = lst[b * CAP + threadIdx.x];
        bool ist = false;
        for (int t = 0; t < N_SLOTS; ++t) ist |= (tps[t] == en.y);
        if (ist) { en.y |= TFLAG; lst[b * CAP + threadIdx.x] = en; }
    }
}

// one block (256 thr) per slot: phase A (x0_u, tf_u, q), phase B edge batches
// (scores/v in LDS, dual-half pb to halve barrier count), fused reduce;
// layer 0 scatters relu(agg) into x; layer 1 runs the emb head.
__global__ __launch_bounds__(256) void k_layer(
    const float* __restrict__ nf, const float* __restrict__ x,
    const float* __restrict__ ts, const int* __restrict__ tp,
    const int* __restrict__ cnt, const int2* __restrict__ lst,
    const float* __restrict__ WT_in, const float* __restrict__ inb,
    const float* __restrict__ WT_ft, const float* __restrict__ ftb,
    const float* __restrict__ teW1, const float* __restrict__ teb1,
    const float* __restrict__ WT_te2, const float* __restrict__ teb2,
    const float* __restrict__ WT_q, const float* __restrict__ bq,
    const float* __restrict__ WT_k, const float* __restrict__ bk,
    const float* __restrict__ WT_v, const float* __restrict__ bv,
    const float* __restrict__ WT_ao, const float* __restrict__ aob,
    const float* __restrict__ WT_op, const float* __restrict__ opb,
    const float* __restrict__ WT_o1, const float* __restrict__ o1b,
    const float* __restrict__ WT_o2, const float* __restrict__ o2b,
    float* __restrict__ x_out, float* __restrict__ emb, int layer) {
    __shared__ __align__(16) float xu[128], x0u[128], tfv[128], qv[128], sv[128];
    __shared__ __align__(16) float xs[8 * 128], t1s[8 * 128], x0s[8 * 128], zs[8 * 128];
    __shared__ __align__(16) float4 pb[2 * 8 * 8 * 32];  // 64 KB, two halves
    __shared__ __align__(16) float vbl[CAP * 128];       // 32 KB values
    __shared__ float scl[CAP * 4];
    __shared__ int nbr_s[8], tf_s[8];
    __shared__ float ts_s[8];
    const int slot = blockIdx.x, tid = threadIdx.x, g = tid >> 5, jj = tid & 31;
    const float scale = 0.17677669529663687f;  // 1/sqrt(32)
    const int u = tp[slot];
    const int c = min(cnt[slot], CAP);

    // ---- phase A ----
    if (tid < 128) xu[tid] = (layer == 0) ? nf[(size_t)u * 128 + tid]
                                          : x[(size_t)u * 128 + tid];
    __syncthreads();
    const float* xeff = xu;
    if (layer == 0) {
        pb[g * 32 + jj] = mv_ks1_g8(WT_in, xu, g, jj);
        __syncthreads();
        if (g == 0)
            *(float4*)(x0u + jj * 4) = add4(comb1_g8(pb, jj), *(const float4*)(inb + jj * 4));
        xeff = x0u;
        __syncthreads();
    }
    pb[g * 32 + jj] = mv_ks1_g8(WT_ft, xeff, g, jj);
    __syncthreads();
    if (g == 0)
        *(float4*)(tfv + jj * 4) = add4(comb1_g8(pb, jj), *(const float4*)(ftb + jj * 4));
    __syncthreads();
    pb[g * 32 + jj] = mv_ks1_g8(WT_q, tfv, g, jj);
    __syncthreads();
    if (g == 0)
        *(float4*)(qv + jj * 4) = add4(comb1_g8(pb, jj), *(const float4*)(bq + jj * 4));
    __syncthreads();

    // ---- phase B: edge batches of 8 (item it == group g) ----
    for (int base = 0; base < c; base += 8) {
        if (tid < 8) {
            int i = base + tid;
            int2 en = (i < c) ? lst[slot * CAP + i] : make_int2(0, 0);
            nbr_s[tid] = en.y & ~TFLAG;
            tf_s[tid] = (en.y & TFLAG) ? 1 : 0;
            ts_s[tid] = (i < c) ? ts[en.x] : 0.f;
        }
        __syncthreads();
        {   // stage neighbor row + time-encoding layer-1 activation
            int e = tid >> 5, c0 = jj * 4;
            const float* srcp = (layer == 0) ? (nf + (size_t)nbr_s[e] * 128 + c0)
                                             : (x + (size_t)nbr_s[e] * 128 + c0);
            float4 v = *(const float4*)srcp;
            float* dstp = (layer == 0) ? xs : x0s;
            *(float4*)(dstp + e * 128 + c0) = v;
            float tse = ts_s[e];
            float4 w = *(const float4*)(teW1 + c0);
            float4 b = *(const float4*)(teb1 + c0);
            *(float4*)(t1s + e * 128 + c0) =
                make_float4(fmaxf(fmaf(tse, w.x, b.x), 0.f),
                            fmaxf(fmaf(tse, w.y, b.y), 0.f),
                            fmaxf(fmaf(tse, w.z, b.z), 0.f),
                            fmaxf(fmaf(tse, w.w, b.w), 0.f));
        }
        __syncthreads();
        if (layer == 0) {  // x0_nbr = inW @ nf[nbr] + inb; persist relu(x0)
            float4 acc[8] = {F4Z, F4Z, F4Z, F4Z, F4Z, F4Z, F4Z, F4Z};
            mv8_g8(WT_in, xs, g, jj, acc);
#pragma unroll
            for (int e = 0; e < 8; ++e) pb[(g * 8 + e) * 32 + jj] = acc[e];
            __syncthreads();
            {
                float4 x0v = add4(comb8_g8(pb, g, jj), *(const float4*)(inb + jj * 4));
                *(float4*)(x0s + g * 128 + jj * 4) = x0v;
                if (base + g < c && !tf_s[g])
                    *(float4*)(x_out + (size_t)nbr_s[g] * 128 + jj * 4) = relu4(x0v);
            }
            __syncthreads();
        }
        {   // z = ftW@x0 + ftb + teW2@t1 + teb2 — dual-half pb, single barrier.
            // Sequential scopes: first acc is DEAD (stored to pb) before the
            // second exists — not R8's two-live-acc spill pattern.
            {
                float4 acc[8] = {F4Z, F4Z, F4Z, F4Z, F4Z, F4Z, F4Z, F4Z};
                mv8_g8(WT_ft, x0s, g, jj, acc);
#pragma unroll
                for (int e = 0; e < 8; ++e) pb[(g * 8 + e) * 32 + jj] = acc[e];
            }
            {
                float4 acc[8] = {F4Z, F4Z, F4Z, F4Z, F4Z, F4Z, F4Z, F4Z};
                mv8_g8(WT_te2, t1s, g, jj, acc);
#pragma unroll
                for (int e = 0; e < 8; ++e) pb[2048 + (g * 8 + e) * 32 + jj] = acc[e];
            }
            __syncthreads();
            float4 z4 = add4(add4(comb8_g8(pb, g, jj), comb8_g8(pb + 2048, g, jj)),
                             add4(*(const float4*)(ftb + jj * 4),
                                  *(const float4*)(teb2 + jj * 4)));
            *(float4*)(zs + g * 128 + jj * 4) = z4;
            __syncthreads();
        }
        {   // k and v — dual-half pb, single barrier
            {
                float4 acc[8] = {F4Z, F4Z, F4Z, F4Z, F4Z, F4Z, F4Z, F4Z};
                mv8_g8(WT_k, zs, g, jj, acc);
#pragma unroll
                for (int e = 0; e < 8; ++e) pb[(g * 8 + e) * 32 + jj] = acc[e];
            }
            {
                float4 acc[8] = {F4Z, F4Z, F4Z, F4Z, F4Z, F4Z, F4Z, F4Z};
                mv8_g8(WT_v, zs, g, jj, acc);
#pragma unroll
                for (int e = 0; e < 8; ++e) pb[2048 + (g * 8 + e) * 32 + jj] = acc[e];
            }
            __syncthreads();
            float4 kk = add4(comb8_g8(pb, g, jj), *(const float4*)(bk + jj * 4));
            float4 vv = add4(comb8_g8(pb + 2048, g, jj), *(const float4*)(bv + jj * 4));
            float4 q4 = *(const float4*)(qv + jj * 4);
            float pr = q4.x * kk.x + q4.y * kk.y + q4.z * kk.z + q4.w * kk.w;
            pr += __shfl_xor(pr, 1);
            pr += __shfl_xor(pr, 2);
            pr += __shfl_xor(pr, 4);  // sum over the 8 lanes of head jj>>3
            if (base + g < c) {
                if ((jj & 7) == 0) scl[(base + g) * 4 + (jj >> 3)] = pr * scale;
                *(float4*)(vbl + (base + g) * 128 + jj * 4) = vv;
            }
            __syncthreads();  // before next batch restages LDS
        }
    }

    // ---- fused reduce: softmax over LDS scores + weighted v-sum ----
    if (tid < 128) {
        int h = tid >> 5;
        if (c > 0) {
            float m = -INFINITY;
            for (int i = 0; i < c; ++i) m = fmaxf(m, scl[i * 4 + h]);
            float l = 0.f, o = 0.f;
            for (int i = 0; i < c; ++i) {
                float p = __expf(scl[i * 4 + h] - m);
                l += p;
                o = fmaf(p, vbl[i * 128 + tid], o);
            }
            sv[tid] = o / l;
        } else {
            sv[tid] = 0.f;
        }
    }
    __syncthreads();
    pb[g * 32 + jj] = mv_ks1_g8(WT_ao, sv, g, jj);
    __syncthreads();
    if (g == 0) {
        float4 z4;
        if (c > 0) z4 = add4(comb1_g8(pb, jj), *(const float4*)(aob + jj * 4));
        else z4 = *(const float4*)(tfv + jj * 4);
        *(float4*)(xu + jj * 4) = z4;  // reuse xu as z
    }
    __syncthreads();
    pb[g * 32 + jj] = mv_ks1_g8(WT_op, xu, g, jj);
    __syncthreads();
    if (layer == 0) {
        if (g == 0) {
            float4 a = relu4(add4(comb1_g8(pb, jj), *(const float4*)(opb + jj * 4)));
            *(float4*)(x_out + (size_t)u * 128 + jj * 4) = a;
        }
        return;
    }
    // layer 1: emb head
    if (g == 0)
        *(float4*)(x0u + jj * 4) =
            relu4(add4(comb1_g8(pb, jj), *(const float4*)(opb + jj * 4)));
    __syncthreads();
    pb[g * 32 + jj] = mv_ks1_g8(WT_o1, x0u, g, jj);
    __syncthreads();
    if (g == 0)
        *(float4*)(tfv + jj * 4) =
            relu4(add4(comb1_g8(pb, jj), *(const float4*)(o1b + jj * 4)));
    __syncthreads();
    pb[g * 32 + jj] = mv_ks1_g8_64(WT_o2, tfv, g, jj);
    __syncthreads();
    if (g == 0 && jj < 16)
        *(float4*)(emb + (size_t)slot * 64 + jj * 4) =
            add4(comb1_g8(pb, jj), *(const float4*)(o2b + jj * 4));
}

// one block per pair
__global__ __launch_bounds__(128) void k_pair(
    const float* __restrict__ emb,
    const float* __restrict__ WT_l1, const float* __restrict__ l1b,
    const float* __restrict__ WT_l2, const float* __restrict__ l2b,
    const float* __restrict__ l3W, const float* __restrict__ l3b,
    float* __restrict__ out) {
    __shared__ __align__(16) float pv[128], z1[128], z2s[64];
    __shared__ __align__(16) float4 pb[4 * 32];
    const int p = blockIdx.x, tid = threadIdx.x, g = tid >> 5, jj = tid & 31;
    pv[tid] = (tid < 64) ? emb[(size_t)(2 * p) * 64 + tid]
                         : emb[(size_t)(2 * p + 1) * 64 + (tid - 64)];
    __syncthreads();
    pb[g * 32 + jj] = mv_ks1(WT_l1, pv, g, jj);
    __syncthreads();
    if (g == 0)
        *(float4*)(z1 + jj * 4) = relu4(add4(comb1(pb, jj), *(const float4*)(l1b + jj * 4)));
    __syncthreads();
    pb[g * 32 + jj] = mv_ks1_64(WT_l2, z1, g, jj);
    __syncthreads();
    if (g == 0 && jj < 16)
        *(float4*)(z2s + jj * 4) = relu4(add4(comb1(pb, jj), *(const float4*)(l2b + jj * 4)));
    __syncthreads();
    if (tid < 64) {
        float v = z2s[tid] * l3W[tid];
        v += __shfl_xor(v, 1);
        v += __shfl_xor(v, 2);
        v += __shfl_xor(v, 4);
        v += __shfl_xor(v, 8);
        v += __shfl_xor(v, 16);
        v += __shfl_xor(v, 32);
        if (tid == 0) out[p] = 1.f / (1.f + __expf(-(v + l3b[0])));
    }
}

// ---------- launch ----------
extern "C" void kernel_launch(void* const* d_in, const int* in_sizes, int n_in,
                              void* d_out, int out_size, void* d_ws, size_t ws_size,
                              hipStream_t stream) {
    const float* nf  = (const float*)d_in[0];
    const int*   ei  = (const int*)d_in[1];
    const float* ts  = (const float*)d_in[2];
    const int*   tp  = (const int*)d_in[3];
    const float* inW = (const float*)d_in[4];
    const float* inb = (const float*)d_in[5];
    const float* teW1 = (const float*)d_in[6];
    const float* teb1 = (const float*)d_in[7];
    const float* teW2 = (const float*)d_in[8];
    const float* teb2 = (const float*)d_in[9];
    const float* aiW = (const float*)d_in[10];
    const float* aib = (const float*)d_in[11];
    const float* aoW = (const float*)d_in[12];
    const float* aob = (const float*)d_in[13];
    const float* ftW = (const float*)d_in[14];
    const float* ftb = (const float*)d_in[15];
    const float* opW = (const float*)d_in[16];
    const float* opb = (const float*)d_in[17];
    const float* o1W = (const float*)d_in[18];
    const float* o1b = (const float*)d_in[19];
    const float* o2W = (const float*)d_in[20];
    const float* o2b = (const float*)d_in[21];
    const float* l1W = (const float*)d_in[22];
    const float* l1b = (const float*)d_in[23];
    const float* l2W = (const float*)d_in[24];
    const float* l2b = (const float*)d_in[25];
    const float* l3W = (const float*)d_in[26];
    const float* l3b = (const float*)d_in[27];
    float* out = (float*)d_out;

    char* ws = (char*)d_ws;
    size_t off = 0;
    float* x    = (float*)(ws + off); off += (size_t)N_NODES * 128 * 4;   // 10.24 MB
    int*   cnt  = (int*)  (ws + off); off += N_SLOTS * 4;
    int2*  lst  = (int2*) (ws + off); off += (size_t)N_SLOTS * CAP * 8;
    float* emb  = (float*)(ws + off); off += N_SLOTS * 64 * 4;
    float* WT   = (float*)(ws + off); off += (size_t)NMAT * MSTRIDE * 4;  // 1.2 MB

    k_prep_tr<<<N_SLOTS, 256, 0, stream>>>(ei, tp, inW, ftW, teW2, aiW, aoW, opW,
                                           o1W, o2W, l1W, l2W, WT, cnt, lst);

    for (int l = 0; l < 2; ++l) {
        const float* WT_ft = WT + (1 + l) * MSTRIDE;
        const float* WT_te2 = WT + (3 + l) * MSTRIDE;
        const float* WT_q = WT + (5 + 3 * l) * MSTRIDE;
        const float* WT_k = WT + (6 + 3 * l) * MSTRIDE;
        const float* WT_v = WT + (7 + 3 * l) * MSTRIDE;
        const float* WT_ao = WT + (11 + l) * MSTRIDE;
        const float* WT_op = WT + (13 + l) * MSTRIDE;
        const float* bq = aib + l * 384;
        k_layer<<<N_SLOTS, 256, 0, stream>>>(
            nf, x, ts, tp, cnt, lst,
            WT, inb, WT_ft, ftb + l * 128, teW1 + l * 128, teb1 + l * 128,
            WT_te2, teb2 + l * 128, WT_q, bq, WT_k, bq + 128, WT_v, bq + 256,
            WT_ao, aob + l * 128, WT_op, opb + l * 128,
            WT + 15 * MSTRIDE, o1b, WT + 17 * MSTRIDE, o2b,
            x, emb, l);
    }
    k_pair<<<N_PAIRS, 128, 0, stream>>>(emb, WT + 16 * MSTRIDE, l1b,
                                        WT + 18 * MSTRIDE, l2b, l3W, l3b, out);
}